// Round 5
// baseline (201.578 us; speedup 1.0000x reference)
//
#include <hip/hip_runtime.h>
#include <math.h>

#define BATCH 32
#define CH 768
#define HW 3136           // 56*56
#define HW4 (HW/4)        // 784 float4 per plane
#define HID 48
#define PLANES (BATCH*CH) // 24576
#define WPB 4             // waves per block (256 threads)

typedef float nfloat4 __attribute__((ext_vector_type(4)));

// ---------------- Kernel 1: per-plane avg + max pooling (wave per plane) ----------------
__global__ __launch_bounds__(256) void cbam_pool(const float* __restrict__ x,
                                                 float* __restrict__ avg,
                                                 float* __restrict__ mx) {
    const int wave = threadIdx.x >> 6;
    const int lane = threadIdx.x & 63;
    const int plane = blockIdx.x * WPB + wave;
    const nfloat4* xp = reinterpret_cast<const nfloat4*>(x + (size_t)plane * HW);

    float s = 0.0f;
    float m = -INFINITY;
    for (int i = lane; i < HW4; i += 64) {
        nfloat4 v = xp[i];
        s += (v.x + v.y) + (v.z + v.w);
        m = fmaxf(m, fmaxf(fmaxf(v.x, v.y), fmaxf(v.z, v.w)));
    }
    for (int off = 32; off > 0; off >>= 1) {
        s += __shfl_down(s, off, 64);
        m = fmaxf(m, __shfl_down(m, off, 64));
    }
    if (lane == 0) {
        avg[plane] = s * (1.0f / (float)HW);
        mx[plane]  = m;
    }
}

// ---------------- Kernel 2: shared-MLP + sigmoid gate (all barriers wave-uniform) ----------------
__global__ __launch_bounds__(256) void cbam_mlp(const float* __restrict__ avg,
                                                const float* __restrict__ mx,
                                                const float* __restrict__ w1,   // [HID, CH]
                                                const float* __restrict__ w2,   // [CH, HID]
                                                float* __restrict__ gate) {
    const int b = blockIdx.x;
    __shared__ float sa[CH];
    __shared__ float sv[CH];
    __shared__ float ha[HID];
    __shared__ float hm[HID];
    __shared__ float hsum[HID];

    for (int i = threadIdx.x; i < CH; i += 256) {
        sa[i] = avg[b * CH + i];
        sv[i] = mx[b * CH + i];
    }
    __syncthreads();

    if (threadIdx.x < 2 * HID) {
        const bool is_avg = threadIdx.x < HID;
        const int h = is_avg ? threadIdx.x : threadIdx.x - HID;
        const float4* in4 = reinterpret_cast<const float4*>(is_avg ? sa : sv);
        const float4* wr4 = reinterpret_cast<const float4*>(w1 + (size_t)h * CH);
        float acc = 0.0f;
        #pragma unroll 8
        for (int k = 0; k < CH / 4; ++k) {
            float4 a = in4[k];
            float4 w = wr4[k];
            acc += a.x * w.x + a.y * w.y + a.z * w.z + a.w * w.w;
        }
        float g = 0.5f * acc * (1.0f + erff(acc * 0.70710678118654752f));
        if (is_avg) ha[h] = g; else hm[h] = g;
    }
    __syncthreads();
    if (threadIdx.x < HID) hsum[threadIdx.x] = ha[threadIdx.x] + hm[threadIdx.x];
    __syncthreads();

    for (int c = threadIdx.x; c < CH; c += 256) {
        const float4* wr4 = reinterpret_cast<const float4*>(w2 + (size_t)c * HID);
        const float4* hs4 = reinterpret_cast<const float4*>(hsum);
        float acc = 0.0f;
        #pragma unroll
        for (int h = 0; h < HID / 4; ++h) {
            float4 a = hs4[h];
            float4 w = wr4[h];
            acc += a.x * w.x + a.y * w.y + a.z * w.z + a.w * w.w;
        }
        gate[b * CH + c] = 1.0f / (1.0f + expf(-acc));
    }
}

// ---------------- Kernel 3: scale x by gate (wave per plane, reverse order, PLAIN stores) ----------------
__global__ __launch_bounds__(256) void cbam_scale(const float* __restrict__ x,
                                                  const float* __restrict__ gate,
                                                  float* __restrict__ out) {
    const int wave = threadIdx.x >> 6;
    const int lane = threadIdx.x & 63;
    const int plane = (PLANES - 1) - (blockIdx.x * WPB + wave);
    const float g = gate[plane];
    const nfloat4* xp = reinterpret_cast<const nfloat4*>(x + (size_t)plane * HW);
    nfloat4* op = reinterpret_cast<nfloat4*>(out + (size_t)plane * HW);
    for (int i = lane; i < HW4; i += 64) {
        nfloat4 v = xp[i];
        v.x *= g; v.y *= g; v.z *= g; v.w *= g;
        op[i] = v;                       // plain store (nt removed — A/B vs R4)
    }
}

extern "C" void kernel_launch(void* const* d_in, const int* in_sizes, int n_in,
                              void* d_out, int out_size, void* d_ws, size_t ws_size,
                              hipStream_t stream) {
    const float* x  = (const float*)d_in[0];
    const float* w1 = (const float*)d_in[1];
    const float* w2 = (const float*)d_in[2];
    float* out = (float*)d_out;

    float* avg  = (float*)d_ws;              // PLANES floats
    float* mx   = avg + PLANES;              // PLANES floats
    float* gate = mx + PLANES;               // PLANES floats

    cbam_pool<<<PLANES / WPB, 256, 0, stream>>>(x, avg, mx);
    cbam_mlp<<<BATCH, 256, 0, stream>>>(avg, mx, w1, w2, gate);
    cbam_scale<<<PLANES / WPB, 256, 0, stream>>>(x, gate, out);
}

// Round 6
// 170.107 us; speedup vs baseline: 1.1850x; 1.1850x over previous
//
#include <hip/hip_runtime.h>
#include <math.h>

#define BATCH 32
#define CH 768
#define HW 3136           // 56*56
#define HW4 (HW/4)        // 784 float4 per plane = 3*256 + 16
#define HID 48
#define PLANES (BATCH*CH) // 24576
#define WPB 4             // waves per block (256 threads)

typedef float nfloat4 __attribute__((ext_vector_type(4)));

// ---------------- Kernel 1: per-plane avg + max pooling (wave per plane, 4-deep load batches) ----
__global__ __launch_bounds__(256) void cbam_pool(const float* __restrict__ x,
                                                 float* __restrict__ avg,
                                                 float* __restrict__ mx) {
    const int wave = threadIdx.x >> 6;
    const int lane = threadIdx.x & 63;
    const int plane = blockIdx.x * WPB + wave;
    const nfloat4* xp = reinterpret_cast<const nfloat4*>(x + (size_t)plane * HW);

    float s = 0.0f;
    float m = -INFINITY;
    #pragma unroll
    for (int j = 0; j < 3; ++j) {
        const int base = j * 256 + lane;
        nfloat4 a = xp[base];
        nfloat4 b = xp[base + 64];
        nfloat4 c = xp[base + 128];
        nfloat4 d = xp[base + 192];
        s += ((a.x + a.y) + (a.z + a.w)) + ((b.x + b.y) + (b.z + b.w))
           + ((c.x + c.y) + (c.z + c.w)) + ((d.x + d.y) + (d.z + d.w));
        float ma = fmaxf(fmaxf(a.x, a.y), fmaxf(a.z, a.w));
        float mb = fmaxf(fmaxf(b.x, b.y), fmaxf(b.z, b.w));
        float mc = fmaxf(fmaxf(c.x, c.y), fmaxf(c.z, c.w));
        float md = fmaxf(fmaxf(d.x, d.y), fmaxf(d.z, d.w));
        m = fmaxf(m, fmaxf(fmaxf(ma, mb), fmaxf(mc, md)));
    }
    if (lane < 16) {
        nfloat4 a = xp[768 + lane];
        s += (a.x + a.y) + (a.z + a.w);
        m = fmaxf(m, fmaxf(fmaxf(a.x, a.y), fmaxf(a.z, a.w)));
    }
    for (int off = 32; off > 0; off >>= 1) {
        s += __shfl_down(s, off, 64);
        m = fmaxf(m, __shfl_down(m, off, 64));
    }
    if (lane == 0) {
        avg[plane] = s * (1.0f / (float)HW);
        mx[plane]  = m;
    }
}

// ---------------- Kernel 2: shared-MLP + sigmoid gate (all barriers wave-uniform) ----------------
__global__ __launch_bounds__(256) void cbam_mlp(const float* __restrict__ avg,
                                                const float* __restrict__ mx,
                                                const float* __restrict__ w1,   // [HID, CH]
                                                const float* __restrict__ w2,   // [CH, HID]
                                                float* __restrict__ gate) {
    const int b = blockIdx.x;
    __shared__ float sa[CH];
    __shared__ float sv[CH];
    __shared__ float ha[HID];
    __shared__ float hm[HID];
    __shared__ float hsum[HID];

    for (int i = threadIdx.x; i < CH; i += 256) {
        sa[i] = avg[b * CH + i];
        sv[i] = mx[b * CH + i];
    }
    __syncthreads();

    if (threadIdx.x < 2 * HID) {
        const bool is_avg = threadIdx.x < HID;
        const int h = is_avg ? threadIdx.x : threadIdx.x - HID;
        const float4* in4 = reinterpret_cast<const float4*>(is_avg ? sa : sv);
        const float4* wr4 = reinterpret_cast<const float4*>(w1 + (size_t)h * CH);
        float acc = 0.0f;
        #pragma unroll 8
        for (int k = 0; k < CH / 4; ++k) {
            float4 a = in4[k];
            float4 w = wr4[k];
            acc += a.x * w.x + a.y * w.y + a.z * w.z + a.w * w.w;
        }
        float g = 0.5f * acc * (1.0f + erff(acc * 0.70710678118654752f));
        if (is_avg) ha[h] = g; else hm[h] = g;
    }
    __syncthreads();
    if (threadIdx.x < HID) hsum[threadIdx.x] = ha[threadIdx.x] + hm[threadIdx.x];
    __syncthreads();

    for (int c = threadIdx.x; c < CH; c += 256) {
        const float4* wr4 = reinterpret_cast<const float4*>(w2 + (size_t)c * HID);
        const float4* hs4 = reinterpret_cast<const float4*>(hsum);
        float acc = 0.0f;
        #pragma unroll
        for (int h = 0; h < HID / 4; ++h) {
            float4 a = hs4[h];
            float4 w = wr4[h];
            acc += a.x * w.x + a.y * w.y + a.z * w.z + a.w * w.w;
        }
        gate[b * CH + c] = 1.0f / (1.0f + expf(-acc));
    }
}

// ---------------- Kernel 3: scale (wave per plane, reverse order, nt stores, 4-deep batches) ----
__global__ __launch_bounds__(256) void cbam_scale(const float* __restrict__ x,
                                                  const float* __restrict__ gate,
                                                  float* __restrict__ out) {
    const int wave = threadIdx.x >> 6;
    const int lane = threadIdx.x & 63;
    const int plane = (PLANES - 1) - (blockIdx.x * WPB + wave);
    const float g = gate[plane];
    const nfloat4* xp = reinterpret_cast<const nfloat4*>(x + (size_t)plane * HW);
    nfloat4* op = reinterpret_cast<nfloat4*>(out + (size_t)plane * HW);

    #pragma unroll
    for (int j = 0; j < 3; ++j) {
        const int base = j * 256 + lane;
        nfloat4 a = xp[base];
        nfloat4 b = xp[base + 64];
        nfloat4 c = xp[base + 128];
        nfloat4 d = xp[base + 192];
        a.x *= g; a.y *= g; a.z *= g; a.w *= g;
        b.x *= g; b.y *= g; b.z *= g; b.w *= g;
        c.x *= g; c.y *= g; c.z *= g; c.w *= g;
        d.x *= g; d.y *= g; d.z *= g; d.w *= g;
        __builtin_nontemporal_store(a, &op[base]);
        __builtin_nontemporal_store(b, &op[base + 64]);
        __builtin_nontemporal_store(c, &op[base + 128]);
        __builtin_nontemporal_store(d, &op[base + 192]);
    }
    if (lane < 16) {
        const int i = 768 + lane;
        nfloat4 a = xp[i];
        a.x *= g; a.y *= g; a.z *= g; a.w *= g;
        __builtin_nontemporal_store(a, &op[i]);
    }
}

extern "C" void kernel_launch(void* const* d_in, const int* in_sizes, int n_in,
                              void* d_out, int out_size, void* d_ws, size_t ws_size,
                              hipStream_t stream) {
    const float* x  = (const float*)d_in[0];
    const float* w1 = (const float*)d_in[1];
    const float* w2 = (const float*)d_in[2];
    float* out = (float*)d_out;

    float* avg  = (float*)d_ws;              // PLANES floats
    float* mx   = avg + PLANES;              // PLANES floats
    float* gate = mx + PLANES;               // PLANES floats

    cbam_pool<<<PLANES / WPB, 256, 0, stream>>>(x, avg, mx);
    cbam_mlp<<<BATCH, 256, 0, stream>>>(avg, mx, w1, w2, gate);
    cbam_scale<<<PLANES / WPB, 256, 0, stream>>>(x, gate, out);
}